// Round 6
// baseline (201.562 us; speedup 1.0000x reference)
//
#include <hip/hip_runtime.h>
#include <hip/hip_bf16.h>
#include <stdint.h>

// ---------------- constants ----------------
constexpr int Nn = 8192;
constexpr int Dd = 1024;
constexpr float kAlpha = 0.1f;
constexpr float kEps = 1e-7f;
constexpr float kInf = 3.0e38f;

constexpr int BM = 256, BN = 256, BK = 32;
constexpr int NB = Nn / BM;               // 32 row/col blocks
constexpr int NPAIR = NB * (NB + 1) / 2;  // 528 upper-triangle tile pairs
constexpr int NT = Dd / BK;               // 32 K-steps

using bfx8 = __attribute__((ext_vector_type(8))) __bf16;   // MFMA A/B frag (4 VGPRs)
using f32x4 = __attribute__((ext_vector_type(4))) float;   // MFMA C/D frag

__device__ __forceinline__ unsigned short f2bf(float f) {
  union { float f; unsigned int u; } v; v.f = f;
  unsigned int u = v.u;
  u = u + 0x7fffu + ((u >> 16) & 1u);  // RNE
  return (unsigned short)(u >> 16);
}

__device__ __forceinline__ void min2_insert(float& m1, float& m2, float x) {
  const float lo = fminf(m1, x);
  const float hi = fmaxf(m1, x);
  m1 = lo;
  m2 = fminf(m2, hi);
}

__device__ __forceinline__ void min2_merge(float& m1, float& m2, float o1, float o2) {
  m2 = fminf(fminf(m2, o2), fmaxf(m1, o1));
  m1 = fminf(m1, o1);
}

// ---------------- prep: fp32 -> bf16 + row sq-norms ----------------
__global__ __launch_bounds__(256) void prep_kernel(const float* __restrict__ H,
                                                   unsigned short* __restrict__ Hb,
                                                   float* __restrict__ xn) {
  const int wave = threadIdx.x >> 6;
  const int lane = threadIdx.x & 63;
  const int row = blockIdx.x * 4 + wave;
  const float4* src = (const float4*)(H + (size_t)row * Dd);
  ushort4* dst = (ushort4*)(Hb + (size_t)row * Dd);
  float acc = 0.f;
#pragma unroll
  for (int i = 0; i < 4; ++i) {
    float4 v = src[lane + 64 * i];
    acc = fmaf(v.x, v.x, acc);
    acc = fmaf(v.y, v.y, acc);
    acc = fmaf(v.z, v.z, acc);
    acc = fmaf(v.w, v.w, acc);
    ushort4 o;
    o.x = f2bf(v.x); o.y = f2bf(v.y); o.z = f2bf(v.z); o.w = f2bf(v.w);
    dst[lane + 64 * i] = o;
  }
#pragma unroll
  for (int off = 32; off; off >>= 1) acc += __shfl_xor(acc, off, 64);
  if (lane == 0) xn[row] = acc;
}

// ---------------- main: symmetric fused GEMM + triplet reductions ----------------
// grid = 528 upper-triangle pairs (I<=J) of 256x256 tiles. Rationale: rounds
// 0/1/5 proved the kernel is bound by L3->L2 staging BANDWIDTH (1.04 GB moved
// at 128^2 tiles ~= 8.4 TB/s fabric), not by schedule/latency/conflicts —
// three different K-loop schedules all landed at 122-126 us. 256^2 tiles
// halve bytes-per-FLOP (total staging 528 MB).
//
// 8 waves (512 thr), wave grid 4(wm) x 2(wn), wave tile 64x128:
// acc[4][8] f32x4 = 128 VGPR; __launch_bounds__(512,2) -> 256-reg cap.
// K-loop: round-5 counted-vmcnt structure (3 buffers x 32 KB, stage-ahead 2,
// one raw s_barrier per step, vmcnt(4) never drained in-loop).
// Both-sides XOR swizzle on 64B LDS rows (verified conflict-free r1-r5).
__global__ __launch_bounds__(512, 2) void triplet_main(
    const unsigned short* __restrict__ Hb, const float* __restrict__ xn,
    const int* __restrict__ lab, float* __restrict__ wsMax,
    float* __restrict__ wsM1, float* __restrict__ wsM2) {
  __shared__ __align__(16) unsigned char smem[98304];  // 3 x (16KB A + 16KB B)

  const int tid = threadIdx.x;
  const int wave = tid >> 6;   // 0..7
  const int lane = tid & 63;
  const int quad = lane >> 4;
  const int l15 = lane & 15;
  const int wm = wave & 3;     // row group (64 rows)
  const int wn = wave >> 2;    // col group (128 cols)

  // XCD-aware swizzle: 8 XCDs, contiguous chunk of 66 pairs per XCD (528%8==0).
  int bid = (int)blockIdx.x;
  bid = (bid & 7) * (NPAIR / 8) + (bid >> 3);

  // decode pair index -> (I, J), I <= J
  int b = bid, I = 0;
  while (b >= NB - I) { b -= NB - I; ++I; }
  const int J = I + b;
  const bool diag = (I == J);

  const int rowBase = I * BM;
  const int colBase = J * BN;

  float maxp[16], mn1[16], mn2[16];
#pragma unroll
  for (int s = 0; s < 16; ++s) { maxp[s] = 0.f; mn1[s] = kInf; mn2[s] = kInf; }

  // staging map: wave stages rows [wave*32 + j*16, +16) of BOTH A and B tiles;
  // lane -> (row = lane>>2 within 16-group, 16B slot = lane&3). Slot is
  // XOR-swizzled within the 64B row via the GLOBAL source k-offset (LDS dest
  // stays linear as global_load_lds requires); reads apply the same XOR.
  const int stR = lane >> 2;                                  // local row 0..15
  const int stRow = wave * 32 + stR;                          // tile row (j adds 16)
  const int stCol = ((lane & 3) ^ ((stR >> 1) & 3)) * 8;      // swizzled short off
  const int swq = quad ^ ((l15 >> 1) & 3);                    // read-side swizzle

  f32x4 acc[4][8];
#pragma unroll
  for (int m = 0; m < 4; ++m)
#pragma unroll
    for (int n = 0; n < 8; ++n) acc[m][n] = {0.f, 0.f, 0.f, 0.f};

  auto stage = [&](int bsel, int kt) {
    unsigned short* As = (unsigned short*)(smem + bsel * 32768);
    unsigned short* Bs = (unsigned short*)(smem + bsel * 32768 + 16384);
#pragma unroll
    for (int j = 0; j < 2; ++j) {
      const unsigned short* ga =
          Hb + (size_t)(rowBase + stRow + j * 16) * Dd + kt + stCol;
      __builtin_amdgcn_global_load_lds(
          (const __attribute__((address_space(1))) void*)ga,
          (__attribute__((address_space(3))) void*)&As[(wave * 2 + j) * 512],
          16, 0, 0);
      const unsigned short* gb =
          Hb + (size_t)(colBase + stRow + j * 16) * Dd + kt + stCol;
      __builtin_amdgcn_global_load_lds(
          (const __attribute__((address_space(1))) void*)gb,
          (__attribute__((address_space(3))) void*)&Bs[(wave * 2 + j) * 512],
          16, 0, 0);
    }
  };

  // prologue: stage tiles 0 and 1 (8 loads/wave in flight; no other vmem in
  // the loop so vmcnt accounting is exact: 4 loads per stage per wave).
  stage(0, 0);
  stage(1, BK);

  int cA = 0, cB = 1, cC = 2;
  for (int t = 0; t < NT; ++t) {
    if (t + 1 < NT) {
      asm volatile("s_waitcnt vmcnt(4)" ::: "memory");
    } else {
      asm volatile("s_waitcnt vmcnt(0)" ::: "memory");
    }
    __builtin_amdgcn_s_barrier();
    __builtin_amdgcn_sched_barrier(0);

    if (t + 2 < NT) stage(cC, (t + 2) * BK);

    const unsigned short* As = (const unsigned short*)(smem + cA * 32768);
    const unsigned short* Bs = (const unsigned short*)(smem + cA * 32768 + 16384);
    bfx8 a[4], bb[8];
#pragma unroll
    for (int m = 0; m < 4; ++m)
      a[m] = *(const bfx8*)&As[(wm * 64 + m * 16 + l15) * BK + swq * 8];
#pragma unroll
    for (int n = 0; n < 8; ++n)
      bb[n] = *(const bfx8*)&Bs[(wn * 128 + n * 16 + l15) * BK + swq * 8];
#pragma unroll
    for (int m = 0; m < 4; ++m)
#pragma unroll
      for (int n = 0; n < 8; ++n)
        acc[m][n] = __builtin_amdgcn_mfma_f32_16x16x32_bf16(a[m], bb[n], acc[m][n], 0, 0, 0);

    const int tmp = cA; cA = cB; cB = cC; cC = tmp;
  }

  // ---- epilogue: dist = xr + xc - 2*G; both-sided masked reductions ----
  int lr[16]; float xr[16];
#pragma unroll
  for (int m = 0; m < 4; ++m)
#pragma unroll
    for (int r = 0; r < 4; ++r) {
      const int row = rowBase + wm * 64 + m * 16 + quad * 4 + r;
      lr[m * 4 + r] = lab[row];
      xr[m * 4 + r] = xn[row];
    }
  int lc[8]; float xc[8];
#pragma unroll
  for (int n = 0; n < 8; ++n) {
    const int col = colBase + wn * 128 + n * 16 + l15;
    lc[n] = lab[col];
    xc[n] = xn[col];
  }
  float tmaxp[8], tmn1[8], tmn2[8];
#pragma unroll
  for (int n = 0; n < 8; ++n) { tmaxp[n] = 0.f; tmn1[n] = kInf; tmn2[n] = kInf; }

  if (!diag) {
#pragma unroll
    for (int m = 0; m < 4; ++m)
#pragma unroll
      for (int n = 0; n < 8; ++n)
#pragma unroll
        for (int r = 0; r < 4; ++r) {
          const int s = m * 4 + r;
          const float d = fmaf(-2.f, acc[m][n][r], xr[s] + xc[n]);
          const bool eq = (lr[s] == lc[n]);
          const float pos = eq ? d : 0.f;
          const float dn = eq ? kInf : d;
          maxp[s] = fmaxf(maxp[s], pos);
          min2_insert(mn1[s], mn2[s], dn);
          tmaxp[n] = fmaxf(tmaxp[n], pos);
          min2_insert(tmn1[n], tmn2[n], dn);
        }
  } else {
#pragma unroll
    for (int m = 0; m < 4; ++m)
#pragma unroll
      for (int n = 0; n < 8; ++n)
#pragma unroll
        for (int r = 0; r < 4; ++r) {
          const int s = m * 4 + r;
          // self-pair only possible on the diagonal tile: local row == local col
          const bool selfp =
              (wm * 64 + m * 16 + quad * 4 + r) == (wn * 128 + n * 16 + l15);
          const float d = fmaf(-2.f, acc[m][n][r], xr[s] + xc[n]);
          const bool eq = (lr[s] == lc[n]);
          const float pos = (eq && !selfp) ? d : 0.f;
          const float dn = eq ? kInf : d;  // self is eq -> excluded from negatives
          maxp[s] = fmaxf(maxp[s], pos);
          min2_insert(mn1[s], mn2[s], dn);
        }
  }

  // cross-lane row merge over the 16 column-lanes
#pragma unroll
  for (int off = 1; off < 16; off <<= 1) {
#pragma unroll
    for (int s = 0; s < 16; ++s) {
      const float om = __shfl_xor(maxp[s], off, 64);
      const float o1 = __shfl_xor(mn1[s], off, 64);
      const float o2 = __shfl_xor(mn2[s], off, 64);
      maxp[s] = fmaxf(maxp[s], om);
      min2_merge(mn1[s], mn2[s], o1, o2);
    }
  }

  // ---- LDS scratch phase (reuse staging buffers) ----
  __syncthreads();  // all waves done with staging-buffer ds traffic
  float* rbuf = (float*)smem;          // [4(wm)][64(local)][3] = 768 floats
  float* tbm = ((float*)smem) + 768;   // [4(wm)][2(wn)][4(q)][8(n)][16(l15)] = 4096 each
  float* tb1 = tbm + 4096;
  float* tb2 = tb1 + 4096;

  if (wn == 1 && l15 == 0) {
#pragma unroll
    for (int m = 0; m < 4; ++m)
#pragma unroll
      for (int r = 0; r < 4; ++r) {
        const int s = m * 4 + r;
        const int local = m * 16 + quad * 4 + r;
        rbuf[(wm * 64 + local) * 3 + 0] = maxp[s];
        rbuf[(wm * 64 + local) * 3 + 1] = mn1[s];
        rbuf[(wm * 64 + local) * 3 + 2] = mn2[s];
      }
  }
#pragma unroll
  for (int n = 0; n < 8; ++n) {
    const int idx = (((wm * 2 + wn) * 4 + quad) * 8 + n) * 16 + l15;
    tbm[idx] = tmaxp[n];
    tb1[idx] = tmn1[n];
    tb2[idx] = tmn2[n];
  }
  __syncthreads();

  // row side: wn==0 waves merge rbuf and write P[I][J]
  if (wn == 0 && l15 == 0) {
#pragma unroll
    for (int m = 0; m < 4; ++m)
#pragma unroll
      for (int r = 0; r < 4; ++r) {
        const int s = m * 4 + r;
        const int local = m * 16 + quad * 4 + r;
        float om = rbuf[(wm * 64 + local) * 3 + 0];
        float o1 = rbuf[(wm * 64 + local) * 3 + 1];
        float o2 = rbuf[(wm * 64 + local) * 3 + 2];
        const float M = fmaxf(maxp[s], om);
        float a1 = mn1[s], a2 = mn2[s];
        min2_merge(a1, a2, o1, o2);
        const size_t p = ((size_t)(I * NB + J)) * 256 + wm * 64 + local;
        wsMax[p] = M;
        wsM1[p] = a1;
        wsM2[p] = a2;
      }
  }
  // transposed side: waves with wm<2 merge tbuf over {wm2, quad}, write P[J][I]
  if (wm < 2 && !diag) {
    const int x = wm * 64 + lane;   // col within this wn's 128-col group
    const int tn = x >> 4;          // 0..7
    const int tl = x & 15;
    float M = 0.f, a1 = kInf, a2 = kInf;
#pragma unroll
    for (int wm2 = 0; wm2 < 4; ++wm2)
#pragma unroll
      for (int q = 0; q < 4; ++q) {
        const int idx = (((wm2 * 2 + wn) * 4 + q) * 8 + tn) * 16 + tl;
        M = fmaxf(M, tbm[idx]);
        min2_merge(a1, a2, tb1[idx], tb2[idx]);
      }
    const size_t p = ((size_t)(J * NB + I)) * 256 + wn * 128 + x;
    wsMax[p] = M;
    wsM1[p] = a1;
    wsM2[p] = a2;
  }
}

// ---------------- merge: per-row over 32 col-block partials -> block sums ----
__global__ __launch_bounds__(256) void merge_kernel(
    const float* __restrict__ wsMax, const float* __restrict__ wsM1,
    const float* __restrict__ wsM2, float* __restrict__ bsum,
    float* __restrict__ bcnt) {
  const int r = threadIdx.x;          // 256 rows per block-row, bi == blockIdx.x
  const int bi = blockIdx.x;
  float mp = 0.f, m1 = kInf, m2 = kInf;
#pragma unroll 8
  for (int bj = 0; bj < NB; ++bj) {
    const size_t p = ((size_t)(bi * NB + bj)) * 256 + r;
    mp = fmaxf(mp, wsMax[p]);
    min2_merge(m1, m2, wsM1[p], wsM2[p]);
  }
  const float loss = fmaxf(mp - m2 + kAlpha, 0.f);
  float ls = (loss > kEps) ? loss : 0.f;
  float lc = (loss > kEps) ? 1.f : 0.f;
#pragma unroll
  for (int off = 32; off; off >>= 1) {
    ls += __shfl_down(ls, off, 64);
    lc += __shfl_down(lc, off, 64);
  }
  __shared__ float ss[4], sc[4];
  if ((threadIdx.x & 63) == 0) { ss[threadIdx.x >> 6] = ls; sc[threadIdx.x >> 6] = lc; }
  __syncthreads();
  if (threadIdx.x == 0) {
    bsum[bi] = ss[0] + ss[1] + ss[2] + ss[3];
    bcnt[bi] = sc[0] + sc[1] + sc[2] + sc[3];
  }
}

// ---------------- final: reduce 32 block sums, divide ----------------
__global__ __launch_bounds__(64) void final_kernel(const float* __restrict__ bsum,
                                                   const float* __restrict__ bcnt,
                                                   float* __restrict__ out) {
  float s = (threadIdx.x < NB) ? bsum[threadIdx.x] : 0.f;
  float c = (threadIdx.x < NB) ? bcnt[threadIdx.x] : 0.f;
#pragma unroll
  for (int off = 32; off; off >>= 1) {
    s += __shfl_down(s, off, 64);
    c += __shfl_down(c, off, 64);
  }
  if (threadIdx.x == 0) out[0] = s / c;
}

// ---------------- launch ----------------
extern "C" void kernel_launch(void* const* d_in, const int* in_sizes, int n_in,
                              void* d_out, int out_size, void* d_ws, size_t ws_size,
                              hipStream_t stream) {
  (void)in_sizes; (void)n_in; (void)out_size; (void)ws_size;
  const float* H = (const float*)d_in[0];
  const int* lab = (const int*)d_in[1];
  float* out = (float*)d_out;

  char* ws = (char*)d_ws;
  unsigned short* Hb = (unsigned short*)ws;                              // 16 MB
  float* xn = (float*)(ws + (size_t)Nn * Dd * sizeof(unsigned short));   // 32 KB
  float* wsMax = xn + Nn;                 // 32*32*256 = 256K floats = 1 MB
  float* wsM1 = wsMax + NB * NB * 256;
  float* wsM2 = wsM1 + NB * NB * 256;
  float* bsum = wsM2 + NB * NB * 256;     // 32 floats
  float* bcnt = bsum + NB;

  prep_kernel<<<Nn / 4, 256, 0, stream>>>(H, Hb, xn);
  triplet_main<<<NPAIR, 512, 0, stream>>>(Hb, xn, lab, wsMax, wsM1, wsM2);
  merge_kernel<<<NB, 256, 0, stream>>>(wsMax, wsM1, wsM2, bsum, bcnt);
  final_kernel<<<1, 64, 0, stream>>>(bsum, bcnt, out);
}